// Round 1
// baseline (2436.788 us; speedup 1.0000x reference)
//
#include <hip/hip_runtime.h>
#include <math.h>

#define NSCALES 31
#define WLEN 2048
#define PAD 256
#define FSTRIDE 512
#define NFEAT 95
#define SIM_SIZE (8 * 256 * 256)
#define FEAT_SIZE (8 * 256 * NFEAT)

// ---------------------------------------------------------------------------
// Kernel 1: build per-scale FIR taps hs[m] = -sqrt(s)*(filt[m]-filt[m-1])
// Replicates pywt integrate_wavelet in double precision, then fp32 cast.
// ---------------------------------------------------------------------------
__global__ __launch_bounds__(1024) void build_filters(float* __restrict__ hs_all) {
    __shared__ double ip[1024];
    __shared__ float ff[512];
    const int t = threadIdx.x;

    // xg = linspace(-8, 8, 1024) numpy-style: arange*step + start, endpoint forced
    const double stepp = 16.0 / 1023.0;
    double xi = (double)t * stepp + (-8.0);
    if (t == 1023) xi = 8.0;
    double psi = exp(-(xi * xi) / 2.0) * cos(5.0 * xi);
    ip[t] = psi;
    __syncthreads();

    // inclusive scan (cumsum) in double
    for (int off = 1; off < 1024; off <<= 1) {
        double add = (t >= off) ? ip[t - off] : 0.0;
        __syncthreads();
        ip[t] += add;
        __syncthreads();
    }

    // step = xg[1]-xg[0] as numpy computes it
    double t1 = stepp + (-8.0);
    double step2 = t1 + 8.0;
    ip[t] *= step2;   // int_psi
    __syncthreads();

    for (int s = 1; s <= NSCALES; ++s) {
        const int L = 16 * s + 1;           // filter length (j<1024 never drops)
        const double sstep = (double)s * step2;
        if (t < 512) {
            float fv = 0.f;
            if (t < L) {
                // filt[m] = int_psi[j[L-1-m]], j[i] = trunc(i / (s*step))
                int j = (int)((double)(L - 1 - t) / sstep);
                if (j > 1023) j = 1023;     // safety (never hit)
                fv = (float)ip[j];
            }
            ff[t] = fv;
        }
        __syncthreads();
        if (t < 512) {
            float fm = ff[t];                        // filt[m] (0 for m>=L)
            float fp = (t > 0) ? ff[t - 1] : 0.f;    // filt[m-1]
            hs_all[(s - 1) * FSTRIDE + t] = -sqrtf((float)s) * (fm - fp);
        }
        __syncthreads();
    }
}

// ---------------------------------------------------------------------------
// two-value block sum reduction (result valid on tid 0)
// ---------------------------------------------------------------------------
__device__ inline void block_reduce2(float& v0, float& v1, float* red, int tid) {
#pragma unroll
    for (int o = 32; o >= 1; o >>= 1) {
        v0 += __shfl_xor(v0, o);
        v1 += __shfl_xor(v1, o);
    }
    if ((tid & 63) == 0) {
        red[(tid >> 6)] = v0;
        red[4 + (tid >> 6)] = v1;
    }
    __syncthreads();
    if (tid == 0) {
        v0 = red[0] + red[1] + red[2] + red[3];
        v1 = red[4] + red[5] + red[6] + red[7];
    }
    __syncthreads();
}

// ---------------------------------------------------------------------------
// Kernel 2: per-row CWT (all 31 scales) + fused feature computation.
// One block per (b,n) row. Thread t owns outputs w = 8t..8t+7.
// coef[w] = sum_m hs[m] * xs[PAD + w + 8s - m]
// ---------------------------------------------------------------------------
__global__ __launch_bounds__(256) void cwt_rows(const float* __restrict__ x,
                                                const float* __restrict__ hs_all,
                                                float* __restrict__ cwt_out,
                                                float* __restrict__ feats) {
    __shared__ float xs[PAD + WLEN + PAD];   // 2560 floats
    __shared__ float hls[FSTRIDE];
    __shared__ float red[8];

    const int tid = threadIdx.x;
    const int bn = blockIdx.x;

    // stage row into LDS with zero pads
    {
        const float4* rowv = (const float4*)(x + (size_t)bn * WLEN);
        float4* xsv = (float4*)xs;
        const float4 z4 = make_float4(0.f, 0.f, 0.f, 0.f);
        for (int i = tid; i < WLEN / 4; i += 256) xsv[PAD / 4 + i] = rowv[i];
        if (tid < PAD / 4) {
            xsv[tid] = z4;
            xsv[(PAD + WLEN) / 4 + tid] = z4;
        }
    }

    float sp[8], ssp[8];   // per-w sums over scales: sum p, sum s*p
#pragma unroll
    for (int r = 0; r < 8; ++r) { sp[r] = 0.f; ssp[r] = 0.f; }

    __syncthreads();

    for (int s = 1; s <= NSCALES; ++s) {
        // stage this scale's taps (broadcast reads later)
        ((float2*)hls)[tid] = ((const float2*)(hs_all + (size_t)(s - 1) * FSTRIDE))[tid];
        __syncthreads();

        const int idx0 = PAD + (tid << 3) + (s << 3);   // multiple of 8 -> 16B aligned
        float acc[8];
#pragma unroll
        for (int r = 0; r < 8; ++r) acc[r] = 0.f;

        float4 F1 = *(const float4*)&xs[idx0];
        float4 F2 = *(const float4*)&xs[idx0 + 4];
        int a = idx0 - 4;
        const int nch = 4 * s + 1;   // covers taps 0..16s+3 (padded with zeros)

        for (int c = 0; c < nch; ++c) {
            float4 F0 = *(const float4*)&xs[a];
            a -= 4;
            float4 h = *(const float4*)&hls[c << 2];   // uniform -> broadcast

            // tap m0+0 : window p = 4+r
            acc[0] = fmaf(h.x, F1.x, acc[0]);
            acc[1] = fmaf(h.x, F1.y, acc[1]);
            acc[2] = fmaf(h.x, F1.z, acc[2]);
            acc[3] = fmaf(h.x, F1.w, acc[3]);
            acc[4] = fmaf(h.x, F2.x, acc[4]);
            acc[5] = fmaf(h.x, F2.y, acc[5]);
            acc[6] = fmaf(h.x, F2.z, acc[6]);
            acc[7] = fmaf(h.x, F2.w, acc[7]);
            // tap m0+1 : p = 3+r
            acc[0] = fmaf(h.y, F0.w, acc[0]);
            acc[1] = fmaf(h.y, F1.x, acc[1]);
            acc[2] = fmaf(h.y, F1.y, acc[2]);
            acc[3] = fmaf(h.y, F1.z, acc[3]);
            acc[4] = fmaf(h.y, F1.w, acc[4]);
            acc[5] = fmaf(h.y, F2.x, acc[5]);
            acc[6] = fmaf(h.y, F2.y, acc[6]);
            acc[7] = fmaf(h.y, F2.z, acc[7]);
            // tap m0+2 : p = 2+r
            acc[0] = fmaf(h.z, F0.z, acc[0]);
            acc[1] = fmaf(h.z, F0.w, acc[1]);
            acc[2] = fmaf(h.z, F1.x, acc[2]);
            acc[3] = fmaf(h.z, F1.y, acc[3]);
            acc[4] = fmaf(h.z, F1.z, acc[4]);
            acc[5] = fmaf(h.z, F1.w, acc[5]);
            acc[6] = fmaf(h.z, F2.x, acc[6]);
            acc[7] = fmaf(h.z, F2.y, acc[7]);
            // tap m0+3 : p = 1+r
            acc[0] = fmaf(h.w, F0.y, acc[0]);
            acc[1] = fmaf(h.w, F0.z, acc[1]);
            acc[2] = fmaf(h.w, F0.w, acc[2]);
            acc[3] = fmaf(h.w, F1.x, acc[3]);
            acc[4] = fmaf(h.w, F1.y, acc[4]);
            acc[5] = fmaf(h.w, F1.z, acc[5]);
            acc[6] = fmaf(h.w, F1.w, acc[6]);
            acc[7] = fmaf(h.w, F2.x, acc[7]);

            F2 = F1;
            F1 = F0;
        }

        // store cwt coefficients (coalesced float4 x2)
        {
            size_t off = ((size_t)bn * NSCALES + (size_t)(s - 1)) * WLEN + (size_t)(tid << 3);
            *(float4*)(cwt_out + off) = make_float4(acc[0], acc[1], acc[2], acc[3]);
            *(float4*)(cwt_out + off + 4) = make_float4(acc[4], acc[5], acc[6], acc[7]);
        }

        // per-scale stats + per-w centroid accumulators
        float sa = 0.f, sq = 0.f;
        const float fs = (float)s;
#pragma unroll
        for (int r = 0; r < 8; ++r) {
            float av = fabsf(acc[r]);
            float p = acc[r] * acc[r];
            sa += av;
            sq += p;
            sp[r] += p;
            ssp[r] = fmaf(fs, p, ssp[r]);
        }
        block_reduce2(sa, sq, red, tid);
        if (tid == 0) {
            float mean = sa * (1.f / 2048.f);
            float var = sq * (1.f / 2048.f) - mean * mean;
            feats[(size_t)bn * NFEAT + (s - 1)] = mean;
            feats[(size_t)bn * NFEAT + 31 + (s - 1)] = var;
            feats[(size_t)bn * NFEAT + 62 + (s - 1)] = sq;
        }
        __syncthreads();   // protects red + hls for next scale
    }

    // spectral centroid mean/std over w
    float cs0 = 0.f, cs2 = 0.f;
#pragma unroll
    for (int r = 0; r < 8; ++r) {
        float cen = ssp[r] / (sp[r] + 1e-8f);
        cs0 += cen;
        cs2 = fmaf(cen, cen, cs2);
    }
    block_reduce2(cs0, cs2, red, tid);
    if (tid == 0) {
        float cm = cs0 * (1.f / 2048.f);
        float var = cs2 * (1.f / 2048.f) - cm * cm;
        feats[(size_t)bn * NFEAT + 93] = cm;
        feats[(size_t)bn * NFEAT + 94] = sqrtf(fmaxf(var, 0.f));
    }
}

// ---------------------------------------------------------------------------
// Kernel 3: cosine similarity. Block = (b,i); thread j computes sim[b,i,j].
// ---------------------------------------------------------------------------
__global__ __launch_bounds__(256) void cosine_sim(const float* __restrict__ feats,
                                                  float* __restrict__ sim) {
    __shared__ float fi[NFEAT];
    const int tid = threadIdx.x;
    const int bn = blockIdx.x;
    const int b = bn >> 8;
    const int i = bn & 255;
    const float* fbase = feats + (size_t)b * 256 * NFEAT;

    if (tid < NFEAT) fi[tid] = fbase[(size_t)i * NFEAT + tid];
    __syncthreads();

    const float* fj = fbase + (size_t)tid * NFEAT;
    float dot = 0.f, ni = 0.f, nj = 0.f;
    for (int d = 0; d < NFEAT; ++d) {
        float va = fi[d];
        float vb = fj[d];
        dot = fmaf(va, vb, dot);
        ni = fmaf(va, va, ni);
        nj = fmaf(vb, vb, nj);
    }
    float norm_i = sqrtf(ni);
    float norm_j = sqrtf(nj);
    float inv_i = (norm_i == 0.f) ? 1.f : 1.f / norm_i;
    float inv_j = (norm_j == 0.f) ? 1.f : 1.f / norm_j;
    sim[(size_t)b * 65536 + (size_t)i * 256 + (size_t)tid] = dot * inv_i * inv_j;
}

// ---------------------------------------------------------------------------
extern "C" void kernel_launch(void* const* d_in, const int* in_sizes, int n_in,
                              void* d_out, int out_size, void* d_ws, size_t ws_size,
                              hipStream_t stream) {
    (void)in_sizes; (void)n_in; (void)out_size; (void)ws_size;
    const float* x = (const float*)d_in[0];
    float* out = (float*)d_out;

    float* sim = out;
    float* feats = out + SIM_SIZE;
    float* cwt = out + SIM_SIZE + FEAT_SIZE;
    float* hs_all = (float*)d_ws;   // 31 * 512 floats

    build_filters<<<1, 1024, 0, stream>>>(hs_all);
    cwt_rows<<<2048, 256, 0, stream>>>(x, hs_all, cwt, feats);
    cosine_sim<<<2048, 256, 0, stream>>>(feats, sim);
}

// Round 2
// 2015.806 us; speedup vs baseline: 1.2088x; 1.2088x over previous
//
#include <hip/hip_runtime.h>
#include <math.h>

#define NSCALES 31
#define WLEN 2048
#define PAD 256
#define FSTRIDE 512
#define NFEAT 95
#define SIM_SIZE (8 * 256 * 256)
#define FEAT_SIZE (8 * 256 * NFEAT)

// ---------------------------------------------------------------------------
// Kernel 1: build per-scale FIR taps hs[m] = -sqrt(s)*(filt[m]-filt[m-1])
// Replicates pywt integrate_wavelet in double precision, then fp32 cast.
// ---------------------------------------------------------------------------
__global__ __launch_bounds__(1024) void build_filters(float* __restrict__ hs_all) {
    __shared__ double ip[1024];
    __shared__ float ff[512];
    const int t = threadIdx.x;

    // xg = linspace(-8, 8, 1024) numpy-style: arange*step + start, endpoint forced
    const double stepp = 16.0 / 1023.0;
    double xi = (double)t * stepp + (-8.0);
    if (t == 1023) xi = 8.0;
    double psi = exp(-(xi * xi) / 2.0) * cos(5.0 * xi);
    ip[t] = psi;
    __syncthreads();

    // inclusive scan (cumsum) in double
    for (int off = 1; off < 1024; off <<= 1) {
        double add = (t >= off) ? ip[t - off] : 0.0;
        __syncthreads();
        ip[t] += add;
        __syncthreads();
    }

    // step = xg[1]-xg[0] as numpy computes it
    double t1 = stepp + (-8.0);
    double step2 = t1 + 8.0;
    ip[t] *= step2;   // int_psi
    __syncthreads();

    for (int s = 1; s <= NSCALES; ++s) {
        const int L = 16 * s + 1;           // filter length (j<1024 never drops)
        const double sstep = (double)s * step2;
        if (t < 512) {
            float fv = 0.f;
            if (t < L) {
                // filt[m] = int_psi[j[L-1-m]], j[i] = trunc(i / (s*step))
                int j = (int)((double)(L - 1 - t) / sstep);
                if (j > 1023) j = 1023;     // safety (never hit)
                fv = (float)ip[j];
            }
            ff[t] = fv;
        }
        __syncthreads();
        if (t < 512) {
            float fm = ff[t];                        // filt[m] (0 for m>=L)
            float fp = (t > 0) ? ff[t - 1] : 0.f;    // filt[m-1]
            hs_all[(s - 1) * FSTRIDE + t] = -sqrtf((float)s) * (fm - fp);
        }
        __syncthreads();
    }
}

// ---------------------------------------------------------------------------
// two-value block sum reduction (result valid on tid 0)
// ---------------------------------------------------------------------------
__device__ inline void block_reduce2(float& v0, float& v1, float* red, int tid) {
#pragma unroll
    for (int o = 32; o >= 1; o >>= 1) {
        v0 += __shfl_xor(v0, o);
        v1 += __shfl_xor(v1, o);
    }
    if ((tid & 63) == 0) {
        red[(tid >> 6)] = v0;
        red[4 + (tid >> 6)] = v1;
    }
    __syncthreads();
    if (tid == 0) {
        v0 = red[0] + red[1] + red[2] + red[3];
        v1 = red[4] + red[5] + red[6] + red[7];
    }
    __syncthreads();
}

// ---------------------------------------------------------------------------
// 4-tap x 4-output FIR block. Window: F1 = xs[p..p+3], F0 = xs[p-4..p-1],
// out[j] = sum_d h[d] * xs[p + j - d]
// ---------------------------------------------------------------------------
__device__ inline void fir4(const float4 h, const float4 F1, const float4 F0,
                            float* __restrict__ acc) {
    acc[0] = fmaf(h.x, F1.x, acc[0]);
    acc[1] = fmaf(h.x, F1.y, acc[1]);
    acc[2] = fmaf(h.x, F1.z, acc[2]);
    acc[3] = fmaf(h.x, F1.w, acc[3]);
    acc[0] = fmaf(h.y, F0.w, acc[0]);
    acc[1] = fmaf(h.y, F1.x, acc[1]);
    acc[2] = fmaf(h.y, F1.y, acc[2]);
    acc[3] = fmaf(h.y, F1.z, acc[3]);
    acc[0] = fmaf(h.z, F0.z, acc[0]);
    acc[1] = fmaf(h.z, F0.w, acc[1]);
    acc[2] = fmaf(h.z, F1.x, acc[2]);
    acc[3] = fmaf(h.z, F1.y, acc[3]);
    acc[0] = fmaf(h.w, F0.y, acc[0]);
    acc[1] = fmaf(h.w, F0.z, acc[1]);
    acc[2] = fmaf(h.w, F0.w, acc[2]);
    acc[3] = fmaf(h.w, F1.x, acc[3]);
}

// ---------------------------------------------------------------------------
// Kernel 2: per-row CWT (all 31 scales) + fused feature computation.
// One block per (b,n) row. Thread t owns outputs w = 4t..4t+3 (group A)
// and w = 4t+1024..4t+1027 (group B)  -> lane-stride-16B LDS reads, no
// bank-group aliasing (round-1 had 16-way conflicts, 9.5e8 counter).
// coef[w] = sum_m hs[m] * xs[PAD + w + 8s - m]
// ---------------------------------------------------------------------------
__global__ __launch_bounds__(256) void cwt_rows(const float* __restrict__ x,
                                                const float* __restrict__ hs_all,
                                                float* __restrict__ cwt_out,
                                                float* __restrict__ feats) {
    __shared__ float xs[PAD + WLEN + PAD];   // 2560 floats
    __shared__ float hls[FSTRIDE];
    __shared__ float red[8];

    const int tid = threadIdx.x;
    const int bn = blockIdx.x;

    // stage row into LDS with zero pads
    {
        const float4* rowv = (const float4*)(x + (size_t)bn * WLEN);
        float4* xsv = (float4*)xs;
        const float4 z4 = make_float4(0.f, 0.f, 0.f, 0.f);
        for (int i = tid; i < WLEN / 4; i += 256) xsv[PAD / 4 + i] = rowv[i];
        if (tid < PAD / 4) {
            xsv[tid] = z4;
            xsv[(PAD + WLEN) / 4 + tid] = z4;
        }
    }

    float sp[8], ssp[8];   // per-w sums over scales: sum p, sum s*p
#pragma unroll
    for (int r = 0; r < 8; ++r) { sp[r] = 0.f; ssp[r] = 0.f; }

    __syncthreads();

    for (int s = 1; s <= NSCALES; ++s) {
        // stage this scale's taps (uniform broadcast reads later)
        ((float2*)hls)[tid] = ((const float2*)(hs_all + (size_t)(s - 1) * FSTRIDE))[tid];
        __syncthreads();

        const int base0 = PAD + (tid << 2) + (s << 3);   // 16B aligned
        const int base1 = base0 + 1024;

        float accA[4] = {0.f, 0.f, 0.f, 0.f};
        float accB[4] = {0.f, 0.f, 0.f, 0.f};

        float4 A1 = *(const float4*)&xs[base0];
        float4 B1 = *(const float4*)&xs[base1];
        int aA = base0 - 4;
        int aB = base1 - 4;
        float4 A0 = *(const float4*)&xs[aA]; aA -= 4;
        float4 B0 = *(const float4*)&xs[aB]; aB -= 4;

        const int nch = 4 * s + 1;   // covers taps 0..16s+3 (zero-padded)

        for (int c = 0; c < nch; ++c) {
            // prefetch next window chunk (stays in-bounds: min addr = 0 at t=0,s=31)
            float4 A0n = *(const float4*)&xs[aA]; aA -= 4;
            float4 B0n = *(const float4*)&xs[aB]; aB -= 4;
            float4 h = *(const float4*)&hls[c << 2];   // uniform -> broadcast

            fir4(h, A1, A0, accA);
            fir4(h, B1, B0, accB);

            A1 = A0; A0 = A0n;
            B1 = B0; B0 = B0n;
        }

        // store cwt coefficients (coalesced float4, lane-contiguous)
        {
            size_t off = ((size_t)bn * NSCALES + (size_t)(s - 1)) * WLEN + (size_t)(tid << 2);
            *(float4*)(cwt_out + off) = make_float4(accA[0], accA[1], accA[2], accA[3]);
            *(float4*)(cwt_out + off + 1024) = make_float4(accB[0], accB[1], accB[2], accB[3]);
        }

        // per-scale stats + per-w centroid accumulators
        float sa = 0.f, sq = 0.f;
        const float fs = (float)s;
#pragma unroll
        for (int r = 0; r < 4; ++r) {
            float av = fabsf(accA[r]);
            float p = accA[r] * accA[r];
            sa += av; sq += p;
            sp[r] += p;
            ssp[r] = fmaf(fs, p, ssp[r]);
        }
#pragma unroll
        for (int r = 0; r < 4; ++r) {
            float av = fabsf(accB[r]);
            float p = accB[r] * accB[r];
            sa += av; sq += p;
            sp[4 + r] += p;
            ssp[4 + r] = fmaf(fs, p, ssp[4 + r]);
        }
        block_reduce2(sa, sq, red, tid);
        if (tid == 0) {
            float mean = sa * (1.f / 2048.f);
            float var = sq * (1.f / 2048.f) - mean * mean;
            feats[(size_t)bn * NFEAT + (s - 1)] = mean;
            feats[(size_t)bn * NFEAT + 31 + (s - 1)] = var;
            feats[(size_t)bn * NFEAT + 62 + (s - 1)] = sq;
        }
        __syncthreads();   // protects red + hls for next scale
    }

    // spectral centroid mean/std over w
    float cs0 = 0.f, cs2 = 0.f;
#pragma unroll
    for (int r = 0; r < 8; ++r) {
        float cen = ssp[r] / (sp[r] + 1e-8f);
        cs0 += cen;
        cs2 = fmaf(cen, cen, cs2);
    }
    block_reduce2(cs0, cs2, red, tid);
    if (tid == 0) {
        float cm = cs0 * (1.f / 2048.f);
        float var = cs2 * (1.f / 2048.f) - cm * cm;
        feats[(size_t)bn * NFEAT + 93] = cm;
        feats[(size_t)bn * NFEAT + 94] = sqrtf(fmaxf(var, 0.f));
    }
}

// ---------------------------------------------------------------------------
// Kernel 3: cosine similarity. Block = (b,i); thread j computes sim[b,i,j].
// ---------------------------------------------------------------------------
__global__ __launch_bounds__(256) void cosine_sim(const float* __restrict__ feats,
                                                  float* __restrict__ sim) {
    __shared__ float fi[NFEAT];
    const int tid = threadIdx.x;
    const int bn = blockIdx.x;
    const int b = bn >> 8;
    const int i = bn & 255;
    const float* fbase = feats + (size_t)b * 256 * NFEAT;

    if (tid < NFEAT) fi[tid] = fbase[(size_t)i * NFEAT + tid];
    __syncthreads();

    const float* fj = fbase + (size_t)tid * NFEAT;
    float dot = 0.f, ni = 0.f, nj = 0.f;
    for (int d = 0; d < NFEAT; ++d) {
        float va = fi[d];
        float vb = fj[d];
        dot = fmaf(va, vb, dot);
        ni = fmaf(va, va, ni);
        nj = fmaf(vb, vb, nj);
    }
    float norm_i = sqrtf(ni);
    float norm_j = sqrtf(nj);
    float inv_i = (norm_i == 0.f) ? 1.f : 1.f / norm_i;
    float inv_j = (norm_j == 0.f) ? 1.f : 1.f / norm_j;
    sim[(size_t)b * 65536 + (size_t)i * 256 + (size_t)tid] = dot * inv_i * inv_j;
}

// ---------------------------------------------------------------------------
extern "C" void kernel_launch(void* const* d_in, const int* in_sizes, int n_in,
                              void* d_out, int out_size, void* d_ws, size_t ws_size,
                              hipStream_t stream) {
    (void)in_sizes; (void)n_in; (void)out_size; (void)ws_size;
    const float* x = (const float*)d_in[0];
    float* out = (float*)d_out;

    float* sim = out;
    float* feats = out + SIM_SIZE;
    float* cwt = out + SIM_SIZE + FEAT_SIZE;
    float* hs_all = (float*)d_ws;   // 31 * 512 floats

    build_filters<<<1, 1024, 0, stream>>>(hs_all);
    cwt_rows<<<2048, 256, 0, stream>>>(x, hs_all, cwt, feats);
    cosine_sim<<<2048, 256, 0, stream>>>(feats, sim);
}